// Round 3
// baseline (377.996 us; speedup 1.0000x reference)
//
#include <hip/hip_runtime.h>

#define NNODES 50000
#define NEDGES 200000
#define NSCANB ((NNODES + 255) / 256)   // 196 scan blocks

typedef short  bf16x8 __attribute__((ext_vector_type(8)));
typedef float  f32x4  __attribute__((ext_vector_type(4)));
typedef unsigned int u32x4 __attribute__((ext_vector_type(4)));

__device__ __forceinline__ unsigned short f2bf(float f) {
    union { float f; unsigned int u; } c; c.f = f;
    unsigned int r = c.u + 0x7fffu + ((c.u >> 16) & 1u);
    return (unsigned short)(r >> 16);
}
__device__ __forceinline__ float bflo(unsigned int v) {
    union { unsigned int u; float f; } c; c.u = v << 16;
    return c.f;
}
__device__ __forceinline__ float bfhi(unsigned int v) {
    union { unsigned int u; float f; } c; c.u = v & 0xffff0000u;
    return c.f;
}

// ---------------- fused prep + edge count (wide grid-stride) ----------------
// deg[] is zeroed by hipMemsetAsync before this launch.
#define PREP_B1 (256 * 1024)
#define PREP_B2 (64 * 512)
#define PREP_XC (NNODES * 64)
__global__ __launch_bounds__(256) void k_prepcount(const float* __restrict__ x,
                                                   const float* __restrict__ W1_rel,
                                                   const float* __restrict__ W1_root,
                                                   const float* __restrict__ W2_rel,
                                                   const float* __restrict__ W2_root,
                                                   const int* __restrict__ ei,
                                                   int* __restrict__ deg,
                                                   unsigned short* __restrict__ Bt1,
                                                   unsigned short* __restrict__ Bt2,
                                                   unsigned short* __restrict__ xb) {
    const int gtid = blockIdx.x * 256 + threadIdx.x;
    const int GS = gridDim.x * 256;
    for (int e = gtid; e < NEDGES; e += GS) atomicAdd(&deg[ei[NEDGES + e]], 1);
    for (int i = gtid; i < PREP_B1; i += GS) {
        int n = i >> 10, k = i & 1023;
        float v = (k < 512) ? W1_rel[k * 256 + n] : W1_root[(k - 512) * 256 + n];
        Bt1[i] = f2bf(v);
    }
    for (int i = gtid; i < PREP_B2; i += GS) {
        int n = i >> 9, k = i & 511;
        float v = (k < 256) ? W2_rel[k * 64 + n] : W2_root[(k - 256) * 64 + n];
        Bt2[i] = f2bf(v);
    }
    for (int i = gtid; i < PREP_XC; i += GS) {
        int n = i >> 6, c8 = (i & 63) * 8;
        const float* xp = x + (size_t)n * 512 + c8;
        float4 a = *(const float4*)xp;
        float4 bb = *(const float4*)(xp + 4);
        unsigned short o[8];
        o[0] = f2bf(a.x); o[1] = f2bf(a.y); o[2] = f2bf(a.z); o[3] = f2bf(a.w);
        o[4] = f2bf(bb.x); o[5] = f2bf(bb.y); o[6] = f2bf(bb.z); o[7] = f2bf(bb.w);
        *(u32x4*)(xb + (size_t)n * 512 + c8) = *(const u32x4*)o;
    }
}

// ---------------- CSR scan: block-local exclusive ----------------
__global__ __launch_bounds__(256) void k_scanA(const int* __restrict__ deg,
                                               int* __restrict__ rs,
                                               int* __restrict__ partials) {
    __shared__ int sm[256];
    int t = threadIdx.x, i = blockIdx.x * 256 + t;
    int v = (i < NNODES) ? deg[i] : 0;
    sm[t] = v;
    __syncthreads();
#pragma unroll
    for (int off = 1; off < 256; off <<= 1) {
        int u = (t >= off) ? sm[t - off] : 0;
        __syncthreads();
        sm[t] += u;
        __syncthreads();
    }
    if (i < NNODES) rs[i] = sm[t] - v;
    if (t == 255) partials[blockIdx.x] = sm[255];
}

// fused scanB+scanC: each block reduces partials[0..b-1] itself (196 ints)
__global__ __launch_bounds__(256) void k_scanC2(int* __restrict__ rs,
                                                const int* __restrict__ partials,
                                                int* __restrict__ cursor) {
    __shared__ int sm[256];
    int t = threadIdx.x, b = blockIdx.x;
    sm[t] = (t < b && t < NSCANB) ? partials[t] : 0;
    __syncthreads();
#pragma unroll
    for (int off = 128; off; off >>= 1) {
        if (t < off) sm[t] += sm[t + off];
        __syncthreads();
    }
    int off0 = sm[0];
    int i = b * 256 + t;
    if (i < NNODES) {
        int rv = rs[i] + off0;
        rs[i] = rv;
        cursor[i] = rv;
    }
    if (i == 0) rs[NNODES] = NEDGES;
}

__global__ void k_scatter(const int* __restrict__ ei, int* __restrict__ cursor,
                          int* __restrict__ srcs) {
    int e = blockIdx.x * 256 + threadIdx.x;
    if (e < NEDGES) {
        int d = ei[NEDGES + e];
        int p = atomicAdd(&cursor[d], 1);
        srcs[p] = ei[e];
    }
}

// ---------------- GEMM1 with FUSED softmax aggregation ---------------------
// 64x256 tile, 512 threads (8 waves, 2x4). K=1024: kt<512 -> A-slice computed
// in-register from gathered xb neighbor slices (per-feature softmax agg is
// K-sliceable), ds_write swizzled into As. kt>=512 -> direct global_load_lds
// of xb (root path). No AggBuf materialization.
// LDS convention: As/Bs[r][cb] = global[r][cb ^ (r&7)] (cb = 8-elem block).
__global__ __launch_bounds__(512) void k_gemm1f(const unsigned short* __restrict__ xb,
                                                const unsigned short* __restrict__ Bt,
                                                const int* __restrict__ rs,
                                                const int* __restrict__ srcs,
                                                const float* __restrict__ r1,
                                                const float* __restrict__ r2,
                                                const float* __restrict__ bias,
                                                unsigned short* __restrict__ outp) {
    constexpr int BM = 64, BN = 256, BK = 64;
    __shared__ __align__(16) unsigned short As[BM * BK];   // 8 KB
    __shared__ __align__(16) unsigned short Bs[BN * BK];   // 32 KB
    __shared__ float s1t[BM];

    const int tid = threadIdx.x;
    const int w = tid >> 6;            // 0..7
    const int lane = tid & 63;
    const int lm = lane & 15;
    const int quad = lane >> 4;
    const int wr = w >> 2;             // 0..1
    const int wc = w & 3;              // 0..3
    const int rowbase = blockIdx.x * BM;
    const int wrow = wr * 32;
    const int wcol = wc * 64;
    const int rsub = lane >> 3;        // 0..7
    const int csw = (lane & 7) ^ rsub; // swizzled col-block

    // aggregation mapping: wave covers 8 rows, 8 lanes per row.
    // row = w*8 + rsub; lane's global feature block = lane&7; since
    // (row&7)==rsub, the swizzled store col-block equals csw.
    const int arow = w * 8 + rsub;         // 0..63
    const int acb = lane & 7;
    int g_arow = rowbase + arow;
    if (g_arow >= NNODES) g_arow = NNODES - 1;
    const int ae0 = rs[g_arow], ae1 = rs[g_arow + 1];

    f32x4 acc[2][4];
#pragma unroll
    for (int mi = 0; mi < 2; ++mi)
#pragma unroll
        for (int ni = 0; ni < 4; ++ni) acc[mi][ni] = (f32x4){0.f, 0.f, 0.f, 0.f};

#pragma unroll 1
    for (int kt = 0; kt < 1024; kt += BK) {
        // stage B tile (256 x 64): 4 global_load_lds per thread
#pragma unroll
        for (int l = 0; l < 4; ++l) {
            int r = w * 32 + l * 8;
            const unsigned short* gp = Bt + (size_t)(r + rsub) * 1024 + kt + csw * 8;
            __builtin_amdgcn_global_load_lds(
                (const __attribute__((address_space(1))) void*)gp,
                (__attribute__((address_space(3))) void*)(Bs + r * BK), 16, 0, 0);
        }
        if (kt < 512) {
            // fused softmax-aggregation of this 64-feature slice
            float nu[8], de[8];
#pragma unroll
            for (int j = 0; j < 8; ++j) { nu[j] = 0.f; de[j] = 0.f; }
            const unsigned short* xrow = xb + kt + acb * 8;
            int e = ae0;
            for (; e + 1 < ae1; e += 2) {
                int s0 = srcs[e], s1 = srcs[e + 1];
                u32x4 q0 = *(const u32x4*)(xrow + (size_t)s0 * 512);
                u32x4 q1 = *(const u32x4*)(xrow + (size_t)s1 * 512);
#pragma unroll
                for (int p = 0; p < 4; ++p) {
                    float v0 = bflo(q0[p]), v1 = bfhi(q0[p]);
                    float E0 = __expf(v0), E1 = __expf(v1);
                    de[2 * p] += E0; nu[2 * p] += E0 * v0;
                    de[2 * p + 1] += E1; nu[2 * p + 1] += E1 * v1;
                }
#pragma unroll
                for (int p = 0; p < 4; ++p) {
                    float v0 = bflo(q1[p]), v1 = bfhi(q1[p]);
                    float E0 = __expf(v0), E1 = __expf(v1);
                    de[2 * p] += E0; nu[2 * p] += E0 * v0;
                    de[2 * p + 1] += E1; nu[2 * p + 1] += E1 * v1;
                }
            }
            if (e < ae1) {
                int s0 = srcs[e];
                u32x4 q0 = *(const u32x4*)(xrow + (size_t)s0 * 512);
#pragma unroll
                for (int p = 0; p < 4; ++p) {
                    float v0 = bflo(q0[p]), v1 = bfhi(q0[p]);
                    float E0 = __expf(v0), E1 = __expf(v1);
                    de[2 * p] += E0; nu[2 * p] += E0 * v0;
                    de[2 * p + 1] += E1; nu[2 * p + 1] += E1 * v1;
                }
            }
            unsigned short o[8];
#pragma unroll
            for (int j = 0; j < 8; ++j) o[j] = f2bf(nu[j] / fmaxf(de[j], 1e-16f));
            *(u32x4*)(As + arow * BK + csw * 8) = *(const u32x4*)o;
        } else {
            // root path: direct stage of xb slice, 1 load/thread
            const unsigned short* gp = xb + (size_t)g_arow * 512 + (kt - 512) + csw * 8;
            __builtin_amdgcn_global_load_lds(
                (const __attribute__((address_space(1))) void*)gp,
                (__attribute__((address_space(3))) void*)(As + (w * 8) * BK), 16, 0, 0);
        }
        __syncthreads();
#pragma unroll
        for (int kk = 0; kk < BK; kk += 32) {
            const int kidx = (kk >> 3) + quad;
            const int phys = kidx ^ (lm & 7);
            bf16x8 af[2], bfr[4];
#pragma unroll
            for (int mi = 0; mi < 2; ++mi)
                af[mi] = __builtin_bit_cast(bf16x8,
                    *(const u32x4*)(As + (wrow + mi * 16 + lm) * BK + phys * 8));
#pragma unroll
            for (int ni = 0; ni < 4; ++ni)
                bfr[ni] = __builtin_bit_cast(bf16x8,
                    *(const u32x4*)(Bs + (wcol + ni * 16 + lm) * BK + phys * 8));
#pragma unroll
            for (int mi = 0; mi < 2; ++mi)
#pragma unroll
                for (int ni = 0; ni < 4; ++ni)
                    acc[mi][ni] = __builtin_amdgcn_mfma_f32_16x16x32_bf16(
                        af[mi], bfr[ni], acc[mi][ni], 0, 0, 0);
        }
        __syncthreads();
    }

    // per-row index softmax (max-shifted: values up to 5e4)
    if (tid < BM) {
        int grow = rowbase + tid;
        float r_ = 0.f;
        if (grow < NNODES) {
            int e0 = rs[grow], e1 = rs[grow + 1];
            float m = -INFINITY, d = 0.f, q = 0.f;
            for (int e = e0; e < e1; ++e) {
                float v = (float)srcs[e];
                float nm = fmaxf(m, v);
                float sc = __expf(m - nm), ee = __expf(v - nm);
                d = d * sc + ee;
                q = q * sc + ee * v;
                m = nm;
            }
            r_ = q / fmaxf(d, 1e-16f);
        }
        s1t[tid] = r_;
    }
    __syncthreads();

#pragma unroll
    for (int ni = 0; ni < 4; ++ni) {
        int gc = wcol + ni * 16 + lm;
        float r1v = r1[gc], r2v = r2[gc], bv = bias[gc];
#pragma unroll
        for (int mi = 0; mi < 2; ++mi) {
#pragma unroll
            for (int r = 0; r < 4; ++r) {
                int lrow = wrow + mi * 16 + quad * 4 + r;
                int grow = rowbase + lrow;
                if (grow < NNODES) {
                    float v = acc[mi][ni][r] + s1t[lrow] * r1v + (float)grow * r2v + bv;
                    v = (v >= 0.f) ? v : 0.01f * v;
                    outp[(size_t)grow * 256 + gc] = f2bf(v);
                }
            }
        }
    }
}

// ---------------- GEMM2 + head with FUSED sum aggregation -------------------
// 64x64 tile, 256 threads (4 waves). K=512: kt<256 -> A-slice = segment-sum of
// gathered H1 neighbor slices (two 32-row passes); kt>=256 -> direct stage H1.
__global__ __launch_bounds__(256) void k_gemm2hf(const unsigned short* __restrict__ H1,
                                                 const unsigned short* __restrict__ Bt,
                                                 const int* __restrict__ rs,
                                                 const int* __restrict__ srcs,
                                                 const float* __restrict__ r1,
                                                 const float* __restrict__ r2,
                                                 const float* __restrict__ bias,
                                                 const float* __restrict__ Wp,
                                                 const float* __restrict__ bp,
                                                 const float* __restrict__ Wr,
                                                 const float* __restrict__ br,
                                                 float* __restrict__ out) {
    constexpr int BM = 64, BN = 64, BK = 64;
    __shared__ __align__(16) unsigned short As[BM * BK];   // 8 KB
    __shared__ __align__(16) unsigned short Bs[BN * BK];   // 8 KB
    __shared__ float h2t[BM * 65];
    __shared__ float s1t[BM];

    const int tid = threadIdx.x;
    const int w = tid >> 6;
    const int lane = tid & 63;
    const int lm = lane & 15;
    const int quad = lane >> 4;
    const int rowbase = blockIdx.x * BM;
    const int wrow = w * 16;
    const int rsub = lane >> 3;
    const int csw = (lane & 7) ^ rsub;

    // aggregation: two passes of (4 waves x 8 rows); 8 lanes/row.
    // both pass rows have (row&7)==rsub, so store col-block == csw.
    const int ar0 = w * 8 + rsub;
    const int ar1 = 32 + w * 8 + rsub;
    const int acb = lane & 7;
    int g0 = rowbase + ar0; if (g0 >= NNODES) g0 = NNODES - 1;
    int g1 = rowbase + ar1; if (g1 >= NNODES) g1 = NNODES - 1;
    const int e00 = rs[g0], e01 = rs[g0 + 1];
    const int e10 = rs[g1], e11 = rs[g1 + 1];

    f32x4 acc[4];
#pragma unroll
    for (int ni = 0; ni < 4; ++ni) acc[ni] = (f32x4){0.f, 0.f, 0.f, 0.f};

#pragma unroll 1
    for (int kt = 0; kt < 512; kt += BK) {
        // stage B: 2 loads/thread
#pragma unroll
        for (int l = 0; l < 2; ++l) {
            int r = w * 16 + l * 8;
            const unsigned short* gp = Bt + (size_t)(r + rsub) * 512 + kt + csw * 8;
            __builtin_amdgcn_global_load_lds(
                (const __attribute__((address_space(1))) void*)gp,
                (__attribute__((address_space(3))) void*)(Bs + r * BK), 16, 0, 0);
        }
        if (kt < 256) {
            const unsigned short* hrow = H1 + kt + acb * 8;
#pragma unroll
            for (int pass = 0; pass < 2; ++pass) {
                int ar = pass ? ar1 : ar0;
                int e = pass ? e10 : e00;
                int eend = pass ? e11 : e01;
                float a[8];
#pragma unroll
                for (int j = 0; j < 8; ++j) a[j] = 0.f;
                for (; e + 1 < eend; e += 2) {
                    int s0 = srcs[e], s1 = srcs[e + 1];
                    u32x4 q0 = *(const u32x4*)(hrow + (size_t)s0 * 256);
                    u32x4 q1 = *(const u32x4*)(hrow + (size_t)s1 * 256);
#pragma unroll
                    for (int p = 0; p < 4; ++p) {
                        a[2 * p] += bflo(q0[p]) + bflo(q1[p]);
                        a[2 * p + 1] += bfhi(q0[p]) + bfhi(q1[p]);
                    }
                }
                if (e < eend) {
                    u32x4 q0 = *(const u32x4*)(hrow + (size_t)srcs[e] * 256);
#pragma unroll
                    for (int p = 0; p < 4; ++p) {
                        a[2 * p] += bflo(q0[p]);
                        a[2 * p + 1] += bfhi(q0[p]);
                    }
                }
                unsigned short o[8];
#pragma unroll
                for (int j = 0; j < 8; ++j) o[j] = f2bf(a[j]);
                *(u32x4*)(As + ar * BK + csw * 8) = *(const u32x4*)o;
            }
        } else {
            // root path: direct stage of H1 slice, 2 loads/thread
#pragma unroll
            for (int l = 0; l < 2; ++l) {
                int r = w * 16 + l * 8;
                int gr = rowbase + r + rsub;
                if (gr >= NNODES) gr = NNODES - 1;
                const unsigned short* gp = H1 + (size_t)gr * 256 + (kt - 256) + csw * 8;
                __builtin_amdgcn_global_load_lds(
                    (const __attribute__((address_space(1))) void*)gp,
                    (__attribute__((address_space(3))) void*)(As + r * BK), 16, 0, 0);
            }
        }
        __syncthreads();
#pragma unroll
        for (int kk = 0; kk < BK; kk += 32) {
            const int kidx = (kk >> 3) + quad;
            const int phys = kidx ^ (lm & 7);
            bf16x8 af;
            af = __builtin_bit_cast(bf16x8,
                *(const u32x4*)(As + (wrow + lm) * BK + phys * 8));
            bf16x8 bfr[4];
#pragma unroll
            for (int ni = 0; ni < 4; ++ni)
                bfr[ni] = __builtin_bit_cast(bf16x8,
                    *(const u32x4*)(Bs + (ni * 16 + lm) * BK + phys * 8));
#pragma unroll
            for (int ni = 0; ni < 4; ++ni)
                acc[ni] = __builtin_amdgcn_mfma_f32_16x16x32_bf16(
                    af, bfr[ni], acc[ni], 0, 0, 0);
        }
        __syncthreads();
    }

    // per-row index sum
    if (tid < BM) {
        int grow = rowbase + tid;
        float si = 0.f;
        if (grow < NNODES) {
            int e0 = rs[grow], e1 = rs[grow + 1];
            for (int e = e0; e < e1; ++e) si += (float)srcs[e];
        }
        s1t[tid] = si;
    }
    __syncthreads();

    // epilogue -> LDS h2 tile
#pragma unroll
    for (int ni = 0; ni < 4; ++ni) {
        int gc = ni * 16 + lm;
        float r1v = r1[gc], r2v = r2[gc], bv = bias[gc];
#pragma unroll
        for (int r = 0; r < 4; ++r) {
            int lrow = wrow + quad * 4 + r;
            int grow = rowbase + lrow;
            float v = acc[ni][r] + s1t[lrow] * r1v + (float)grow * r2v + bv;
            v = (v >= 0.f) ? v : 0.01f * v;
            h2t[lrow * 65 + gc] = v;
        }
    }
    __syncthreads();

    // head: threads 0..63, one row each
    if (tid < BM) {
        int grow = rowbase + tid;
        if (grow < NNODES) {
            const float* hv = h2t + tid * 65;
            float idx = (float)grow;
            float p0 = 0.f, p1 = 0.f, p2 = 0.f;
            float r0 = 0.f, r1a = 0.f, r2a = 0.f, r3 = 0.f;
#pragma unroll 8
            for (int c = 0; c < 64; ++c) {
                float v = hv[c];
                p0 += v * Wp[c * 3 + 0];
                p1 += v * Wp[c * 3 + 1];
                p2 += v * Wp[c * 3 + 2];
                r0 += v * Wr[c * 4 + 0];
                r1a += v * Wr[c * 4 + 1];
                r2a += v * Wr[c * 4 + 2];
                r3 += v * Wr[c * 4 + 3];
            }
            p0 += idx * Wp[64 * 3 + 0] + bp[0];
            p1 += idx * Wp[64 * 3 + 1] + bp[1];
            p2 += idx * Wp[64 * 3 + 2] + bp[2];
            r0 += idx * Wr[64 * 4 + 0] + br[0];
            r1a += idx * Wr[64 * 4 + 1] + br[1];
            r2a += idx * Wr[64 * 4 + 2] + br[2];
            r3 += idx * Wr[64 * 4 + 3] + br[3];
            float nrm = fmaxf(sqrtf(r0 * r0 + r1a * r1a + r2a * r2a + r3 * r3), 1e-12f);
            float* op = out + (size_t)grow * 7;
            op[0] = p0; op[1] = p1; op[2] = p2;
            op[3] = r0 / nrm; op[4] = r1a / nrm; op[5] = r2a / nrm; op[6] = r3 / nrm;
        }
    }
}

extern "C" void kernel_launch(void* const* d_in, const int* in_sizes, int n_in,
                              void* d_out, int out_size, void* d_ws, size_t ws_size,
                              hipStream_t stream) {
    const float* x       = (const float*)d_in[0];
    const float* W1_rel  = (const float*)d_in[1];
    const float* b1      = (const float*)d_in[2];
    const float* W1_root = (const float*)d_in[3];
    const float* W2_rel  = (const float*)d_in[4];
    const float* b2      = (const float*)d_in[5];
    const float* W2_root = (const float*)d_in[6];
    const float* Wp      = (const float*)d_in[7];
    const float* bp      = (const float*)d_in[8];
    const float* Wr      = (const float*)d_in[9];
    const float* br      = (const float*)d_in[10];
    const int*   ei      = (const int*)d_in[11];
    float* out = (float*)d_out;

    char* ws = (char*)d_ws;
    size_t off = 0;
    auto alloc = [&](size_t bytes) {
        size_t o = off;
        off = (off + bytes + 255) & ~(size_t)255;
        return (void*)(ws + o);
    };
    int*   deg       = (int*)alloc(NNODES * 4);
    int*   cursor    = (int*)alloc(NNODES * 4);
    int*   row_start = (int*)alloc((NNODES + 1) * 4);
    int*   srcs      = (int*)alloc(NEDGES * 4);
    int*   partials  = (int*)alloc(NSCANB * 4);
    unsigned short* xb     = (unsigned short*)alloc((size_t)NNODES * 512 * 2);
    unsigned short* H1     = (unsigned short*)alloc((size_t)NNODES * 256 * 2);
    unsigned short* Bt1    = (unsigned short*)alloc(256 * 1024 * 2);
    unsigned short* Bt2    = (unsigned short*)alloc(64 * 512 * 2);

    hipMemsetAsync(deg, 0, NNODES * 4, stream);

    k_prepcount<<<2048, 256, 0, stream>>>(
        x, W1_rel, W1_root, W2_rel, W2_root, ei, deg, Bt1, Bt2, xb);

    k_scanA<<<NSCANB, 256, 0, stream>>>(deg, row_start, partials);
    k_scanC2<<<NSCANB, 256, 0, stream>>>(row_start, partials, cursor);
    k_scatter<<<(NEDGES + 255) / 256, 256, 0, stream>>>(ei, cursor, srcs);

    // fused aggregation+GEMM1 -> H1 (bf16, stride 256)
    k_gemm1f<<<(NNODES + 63) / 64, 512, 0, stream>>>(
        xb, Bt1, row_start, srcs, W1_rel + 512 * 256, W1_root + 512 * 256, b1, H1);

    // fused aggregation+GEMM2 + head -> out
    k_gemm2hf<<<(NNODES + 63) / 64, 256, 0, stream>>>(
        H1, Bt2, row_start, srcs, W2_rel + 256 * 64, W2_root + 256 * 64, b2,
        Wp, bp, Wr, br, out);
}

// Round 4
// 339.709 us; speedup vs baseline: 1.1127x; 1.1127x over previous
//
#include <hip/hip_runtime.h>

#define NNODES 50000
#define NEDGES 200000
#define NSCANB ((NNODES + 255) / 256)   // 196 scan blocks

typedef short  bf16x8 __attribute__((ext_vector_type(8)));
typedef float  f32x4  __attribute__((ext_vector_type(4)));
typedef unsigned int u32x4 __attribute__((ext_vector_type(4)));

__device__ __forceinline__ unsigned short f2bf(float f) {
    union { float f; unsigned int u; } c; c.f = f;
    unsigned int r = c.u + 0x7fffu + ((c.u >> 16) & 1u);
    return (unsigned short)(r >> 16);
}
__device__ __forceinline__ float bflo(unsigned int v) {
    union { unsigned int u; float f; } c; c.u = v << 16;
    return c.f;
}
__device__ __forceinline__ float bfhi(unsigned int v) {
    union { unsigned int u; float f; } c; c.u = v & 0xffff0000u;
    return c.f;
}

// ---------------- fused prep + edge count (wide grid-stride) ----------------
// deg[] is zeroed by hipMemsetAsync before this launch.
#define PREP_B1 (256 * 1024)
#define PREP_B2 (64 * 512)
#define PREP_XC (NNODES * 64)
__global__ __launch_bounds__(256) void k_prepcount(const float* __restrict__ x,
                                                   const float* __restrict__ W1_rel,
                                                   const float* __restrict__ W1_root,
                                                   const float* __restrict__ W2_rel,
                                                   const float* __restrict__ W2_root,
                                                   const int* __restrict__ ei,
                                                   int* __restrict__ deg,
                                                   unsigned short* __restrict__ Bt1,
                                                   unsigned short* __restrict__ Bt2,
                                                   unsigned short* __restrict__ xb) {
    const int gtid = blockIdx.x * 256 + threadIdx.x;
    const int GS = gridDim.x * 256;
    for (int e = gtid; e < NEDGES; e += GS) atomicAdd(&deg[ei[NEDGES + e]], 1);
    for (int i = gtid; i < PREP_B1; i += GS) {
        int n = i >> 10, k = i & 1023;
        float v = (k < 512) ? W1_rel[k * 256 + n] : W1_root[(k - 512) * 256 + n];
        Bt1[i] = f2bf(v);
    }
    for (int i = gtid; i < PREP_B2; i += GS) {
        int n = i >> 9, k = i & 511;
        float v = (k < 256) ? W2_rel[k * 64 + n] : W2_root[(k - 256) * 64 + n];
        Bt2[i] = f2bf(v);
    }
    for (int i = gtid; i < PREP_XC; i += GS) {
        int n = i >> 6, c8 = (i & 63) * 8;
        const float* xp = x + (size_t)n * 512 + c8;
        float4 a = *(const float4*)xp;
        float4 bb = *(const float4*)(xp + 4);
        unsigned short o[8];
        o[0] = f2bf(a.x); o[1] = f2bf(a.y); o[2] = f2bf(a.z); o[3] = f2bf(a.w);
        o[4] = f2bf(bb.x); o[5] = f2bf(bb.y); o[6] = f2bf(bb.z); o[7] = f2bf(bb.w);
        *(u32x4*)(xb + (size_t)n * 512 + c8) = *(const u32x4*)o;
    }
}

// ---------------- CSR scan: block-local exclusive ----------------
__global__ __launch_bounds__(256) void k_scanA(const int* __restrict__ deg,
                                               int* __restrict__ rs,
                                               int* __restrict__ partials) {
    __shared__ int sm[256];
    int t = threadIdx.x, i = blockIdx.x * 256 + t;
    int v = (i < NNODES) ? deg[i] : 0;
    sm[t] = v;
    __syncthreads();
#pragma unroll
    for (int off = 1; off < 256; off <<= 1) {
        int u = (t >= off) ? sm[t - off] : 0;
        __syncthreads();
        sm[t] += u;
        __syncthreads();
    }
    if (i < NNODES) rs[i] = sm[t] - v;
    if (t == 255) partials[blockIdx.x] = sm[255];
}

// fused scanB+scanC: each block reduces partials[0..b-1] itself (196 ints)
__global__ __launch_bounds__(256) void k_scanC2(int* __restrict__ rs,
                                                const int* __restrict__ partials,
                                                int* __restrict__ cursor) {
    __shared__ int sm[256];
    int t = threadIdx.x, b = blockIdx.x;
    sm[t] = (t < b && t < NSCANB) ? partials[t] : 0;
    __syncthreads();
#pragma unroll
    for (int off = 128; off; off >>= 1) {
        if (t < off) sm[t] += sm[t + off];
        __syncthreads();
    }
    int off0 = sm[0];
    int i = b * 256 + t;
    if (i < NNODES) {
        int rv = rs[i] + off0;
        rs[i] = rv;
        cursor[i] = rv;
    }
    if (i == 0) rs[NNODES] = NEDGES;
}

__global__ void k_scatter(const int* __restrict__ ei, int* __restrict__ cursor,
                          int* __restrict__ srcs) {
    int e = blockIdx.x * 256 + threadIdx.x;
    if (e < NEDGES) {
        int d = ei[NEDGES + e];
        int p = atomicAdd(&cursor[d], 1);
        srcs[p] = ei[e];
    }
}

// ---------------- softmax aggregation (layer 1): wave-per-node -------------
// 4 nodes/block; lane handles 8 features via one b128 load per edge.
// 4-deep edge unroll for memory-level parallelism (deg ~ 4).
__global__ __launch_bounds__(256) void k_agg1(const unsigned short* __restrict__ xb,
                                              const int* __restrict__ rs,
                                              const int* __restrict__ srcs,
                                              unsigned short* __restrict__ AggBuf) {
    int wv = threadIdx.x >> 6;
    int lane = threadIdx.x & 63;
    int n = blockIdx.x * 4 + wv;
    int e0 = rs[n], e1 = rs[n + 1];
    float nu[8], de[8];
#pragma unroll
    for (int j = 0; j < 8; ++j) { nu[j] = 0.f; de[j] = 0.f; }

    auto accum = [&](u32x4 r) {
#pragma unroll
        for (int p = 0; p < 4; ++p) {
            float v0 = bflo(r[p]), v1 = bfhi(r[p]);
            float E0 = __expf(v0), E1 = __expf(v1);
            de[2 * p] += E0; nu[2 * p] += E0 * v0;
            de[2 * p + 1] += E1; nu[2 * p + 1] += E1 * v1;
        }
    };

    int e = e0;
    for (; e + 3 < e1; e += 4) {
        int s0 = srcs[e], s1 = srcs[e + 1], s2 = srcs[e + 2], s3 = srcs[e + 3];
        u32x4 r0 = *(const u32x4*)(xb + (size_t)s0 * 512 + lane * 8);
        u32x4 r1 = *(const u32x4*)(xb + (size_t)s1 * 512 + lane * 8);
        u32x4 r2 = *(const u32x4*)(xb + (size_t)s2 * 512 + lane * 8);
        u32x4 r3 = *(const u32x4*)(xb + (size_t)s3 * 512 + lane * 8);
        accum(r0); accum(r1); accum(r2); accum(r3);
    }
    if (e + 1 < e1) {
        int s0 = srcs[e], s1 = srcs[e + 1];
        u32x4 r0 = *(const u32x4*)(xb + (size_t)s0 * 512 + lane * 8);
        u32x4 r1 = *(const u32x4*)(xb + (size_t)s1 * 512 + lane * 8);
        accum(r0); accum(r1);
        e += 2;
    }
    if (e < e1) {
        u32x4 r0 = *(const u32x4*)(xb + (size_t)srcs[e] * 512 + lane * 8);
        accum(r0);
    }
    unsigned short o[8];
#pragma unroll
    for (int j = 0; j < 8; ++j) o[j] = f2bf(nu[j] / fmaxf(de[j], 1e-16f));
    *(u32x4*)(AggBuf + (size_t)n * 512 + lane * 8) = *(const u32x4*)o;
}

// ---------------- sum aggregation (layer 2): wave-per-node ------------------
// 4-deep edge unroll for MLP.
__global__ __launch_bounds__(256) void k_agg2(const int* __restrict__ rs,
                                              const int* __restrict__ srcs,
                                              const unsigned short* __restrict__ H1,
                                              unsigned short* __restrict__ Seg) {
    int wv = threadIdx.x >> 6;
    int lane = threadIdx.x & 63;
    int n = blockIdx.x * 4 + wv;
    int e0 = rs[n], e1 = rs[n + 1];
    float a[4] = {0.f, 0.f, 0.f, 0.f};

    auto accum = [&](uint2 r) {
        a[0] += bflo(r.x); a[1] += bfhi(r.x);
        a[2] += bflo(r.y); a[3] += bfhi(r.y);
    };

    int e = e0;
    for (; e + 3 < e1; e += 4) {
        int s0 = srcs[e], s1 = srcs[e + 1], s2 = srcs[e + 2], s3 = srcs[e + 3];
        uint2 r0 = *(const uint2*)(H1 + (size_t)s0 * 256 + lane * 4);
        uint2 r1 = *(const uint2*)(H1 + (size_t)s1 * 256 + lane * 4);
        uint2 r2 = *(const uint2*)(H1 + (size_t)s2 * 256 + lane * 4);
        uint2 r3 = *(const uint2*)(H1 + (size_t)s3 * 256 + lane * 4);
        accum(r0); accum(r1); accum(r2); accum(r3);
    }
    if (e + 1 < e1) {
        int s0 = srcs[e], s1 = srcs[e + 1];
        uint2 r0 = *(const uint2*)(H1 + (size_t)s0 * 256 + lane * 4);
        uint2 r1 = *(const uint2*)(H1 + (size_t)s1 * 256 + lane * 4);
        accum(r0); accum(r1);
        e += 2;
    }
    if (e < e1) {
        uint2 r0 = *(const uint2*)(H1 + (size_t)srcs[e] * 256 + lane * 4);
        accum(r0);
    }
    uint2 o;
    o.x = (unsigned int)f2bf(a[0]) | ((unsigned int)f2bf(a[1]) << 16);
    o.y = (unsigned int)f2bf(a[2]) | ((unsigned int)f2bf(a[3]) << 16);
    *(uint2*)(Seg + (size_t)n * 256 + lane * 4) = o;
}

// ---------------- GEMM1: 64x128 tile, split-A [AggBuf|xb], -> H1 bf16 -------
// 2-stage double-buffered LDS + counted vmcnt(6) (measured 71.4 -> 67.3 us).
__global__ __launch_bounds__(256) void k_gemm1(const unsigned short* __restrict__ A1,
                                               const unsigned short* __restrict__ A2,
                                               const unsigned short* __restrict__ Bt,
                                               const int* __restrict__ rs,
                                               const int* __restrict__ srcs,
                                               const float* __restrict__ r1,
                                               const float* __restrict__ r2,
                                               const float* __restrict__ bias,
                                               unsigned short* __restrict__ outp) {
    constexpr int BM = 64, BN = 128, BK = 64;
    __shared__ __align__(16) unsigned short As[2][BM * BK];
    __shared__ __align__(16) unsigned short Bs[2][BN * BK];
    __shared__ float s1t[BM];

    const int tid = threadIdx.x;
    const int w = tid >> 6;
    const int lane = tid & 63;
    const int lm = lane & 15;
    const int quad = lane >> 4;
    const int wr = w >> 1;
    const int wc = w & 1;
    const int rowbase = blockIdx.y * BM;
    const int colbase = blockIdx.x * BN;
    const int wrow = wr * 32;
    const int wcol = wc * 64;

    const int rsub = lane >> 3;
    const int csw = (lane & 7) ^ rsub;

    f32x4 acc[2][4];
#pragma unroll
    for (int mi = 0; mi < 2; ++mi)
#pragma unroll
        for (int ni = 0; ni < 4; ++ni) acc[mi][ni] = (f32x4){0.f, 0.f, 0.f, 0.f};

    // 6 global_load_lds per thread per stage (2 A + 4 B)
    auto stage = [&](unsigned short* Asb, unsigned short* Bsb, int kt) {
        const unsigned short* Ab = (kt < 512) ? A1 : A2;
        int kof = (kt < 512) ? kt : kt - 512;
#pragma unroll
        for (int l = 0; l < 2; ++l) {
            int r = w * 16 + l * 8;
            int gr = rowbase + r + rsub;
            if (gr >= NNODES) gr = NNODES - 1;
            const unsigned short* gp = Ab + (size_t)gr * 512 + kof + csw * 8;
            __builtin_amdgcn_global_load_lds(
                (const __attribute__((address_space(1))) void*)gp,
                (__attribute__((address_space(3))) void*)(Asb + r * BK), 16, 0, 0);
        }
#pragma unroll
        for (int l = 0; l < 4; ++l) {
            int r = w * 32 + l * 8;
            const unsigned short* gp = Bt + (size_t)(colbase + r + rsub) * 1024 + kt + csw * 8;
            __builtin_amdgcn_global_load_lds(
                (const __attribute__((address_space(1))) void*)gp,
                (__attribute__((address_space(3))) void*)(Bsb + r * BK), 16, 0, 0);
        }
    };

    auto compute = [&](const unsigned short* Asb, const unsigned short* Bsb) {
#pragma unroll
        for (int kk = 0; kk < BK; kk += 32) {
            const int kidx = (kk >> 3) + quad;
            const int phys = kidx ^ (lm & 7);
            bf16x8 af[2], bfr[4];
#pragma unroll
            for (int mi = 0; mi < 2; ++mi)
                af[mi] = __builtin_bit_cast(bf16x8,
                    *(const u32x4*)(Asb + (wrow + mi * 16 + lm) * BK + phys * 8));
#pragma unroll
            for (int ni = 0; ni < 4; ++ni)
                bfr[ni] = __builtin_bit_cast(bf16x8,
                    *(const u32x4*)(Bsb + (wcol + ni * 16 + lm) * BK + phys * 8));
#pragma unroll
            for (int mi = 0; mi < 2; ++mi)
#pragma unroll
                for (int ni = 0; ni < 4; ++ni)
                    acc[mi][ni] = __builtin_amdgcn_mfma_f32_16x16x32_bf16(
                        af[mi], bfr[ni], acc[mi][ni], 0, 0, 0);
        }
    };

    stage(As[0], Bs[0], 0);
#pragma unroll 1
    for (int t = 0; t < 16; t += 2) {
        // phase A: compute buf0 (staged last phase), prefetch buf1
        stage(As[1], Bs[1], (t + 1) * BK);
        asm volatile("s_waitcnt vmcnt(6)" ::: "memory");  // buf0's 6 loads done
        __builtin_amdgcn_s_barrier();
        __builtin_amdgcn_sched_barrier(0);
        compute(As[0], Bs[0]);
        __builtin_amdgcn_s_barrier();
        // phase B: compute buf1, prefetch buf0 (unless last tile)
        if (t + 2 < 16) {
            stage(As[0], Bs[0], (t + 2) * BK);
            asm volatile("s_waitcnt vmcnt(6)" ::: "memory");
        } else {
            asm volatile("s_waitcnt vmcnt(0)" ::: "memory");
        }
        __builtin_amdgcn_s_barrier();
        __builtin_amdgcn_sched_barrier(0);
        compute(As[1], Bs[1]);
        __builtin_amdgcn_s_barrier();
    }

    // per-row index softmax (max-shifted: values up to 5e4)
    if (tid < BM) {
        int grow = rowbase + tid;
        float r_ = 0.f;
        if (grow < NNODES) {
            int e0 = rs[grow], e1 = rs[grow + 1];
            float m = -INFINITY, d = 0.f, q = 0.f;
            for (int e = e0; e < e1; ++e) {
                float v = (float)srcs[e];
                float nm = fmaxf(m, v);
                float sc = __expf(m - nm), ee = __expf(v - nm);
                d = d * sc + ee;
                q = q * sc + ee * v;
                m = nm;
            }
            r_ = q / fmaxf(d, 1e-16f);
        }
        s1t[tid] = r_;
    }
    __syncthreads();

#pragma unroll
    for (int ni = 0; ni < 4; ++ni) {
        int gc = colbase + wcol + ni * 16 + lm;
        float r1v = r1[gc], r2v = r2[gc], bv = bias[gc];
#pragma unroll
        for (int mi = 0; mi < 2; ++mi) {
#pragma unroll
            for (int r = 0; r < 4; ++r) {
                int lrow = wrow + mi * 16 + quad * 4 + r;
                int grow = rowbase + lrow;
                if (grow < NNODES) {
                    float v = acc[mi][ni][r] + s1t[lrow] * r1v + (float)grow * r2v + bv;
                    v = (v >= 0.f) ? v : 0.01f * v;
                    outp[(size_t)grow * 256 + gc] = f2bf(v);
                }
            }
        }
    }
}

// ---------------- GEMM2 + fused head: 64x64 tile, split-A [Seg|H1] ----------
// R0 single-buffered form (known-good).
__global__ __launch_bounds__(256) void k_gemm2h(const unsigned short* __restrict__ A1,
                                                const unsigned short* __restrict__ A2,
                                                const unsigned short* __restrict__ Bt,
                                                const int* __restrict__ rs,
                                                const int* __restrict__ srcs,
                                                const float* __restrict__ r1,
                                                const float* __restrict__ r2,
                                                const float* __restrict__ bias,
                                                const float* __restrict__ Wp,
                                                const float* __restrict__ bp,
                                                const float* __restrict__ Wr,
                                                const float* __restrict__ br,
                                                float* __restrict__ out) {
    constexpr int BM = 64, BN = 64, BK = 64;
    __shared__ __align__(16) unsigned short As[BM * BK];
    __shared__ __align__(16) unsigned short Bs[BN * BK];
    __shared__ float h2t[BM * 65];
    __shared__ float s1t[BM];

    const int tid = threadIdx.x;
    const int w = tid >> 6;
    const int lane = tid & 63;
    const int lm = lane & 15;
    const int quad = lane >> 4;
    const int rowbase = blockIdx.x * BM;
    const int wrow = w * 16;

    const int rsub = lane >> 3;
    const int csw = (lane & 7) ^ rsub;

    f32x4 acc[4];
#pragma unroll
    for (int ni = 0; ni < 4; ++ni) acc[ni] = (f32x4){0.f, 0.f, 0.f, 0.f};

    for (int kt = 0; kt < 512; kt += BK) {
        const unsigned short* Ab = (kt < 256) ? A1 : A2;
        int kof = (kt < 256) ? kt : kt - 256;
#pragma unroll
        for (int l = 0; l < 2; ++l) {
            int r = w * 16 + l * 8;
            int gr = rowbase + r + rsub;
            if (gr >= NNODES) gr = NNODES - 1;
            const unsigned short* gp = Ab + (size_t)gr * 256 + kof + csw * 8;
            __builtin_amdgcn_global_load_lds(
                (const __attribute__((address_space(1))) void*)gp,
                (__attribute__((address_space(3))) void*)(As + r * BK), 16, 0, 0);
        }
#pragma unroll
        for (int l = 0; l < 2; ++l) {
            int r = w * 16 + l * 8;
            const unsigned short* gp = Bt + (size_t)(r + rsub) * 512 + kt + csw * 8;
            __builtin_amdgcn_global_load_lds(
                (const __attribute__((address_space(1))) void*)gp,
                (__attribute__((address_space(3))) void*)(Bs + r * BK), 16, 0, 0);
        }
        __syncthreads();
#pragma unroll
        for (int kk = 0; kk < BK; kk += 32) {
            const int kidx = (kk >> 3) + quad;
            const int phys = kidx ^ (lm & 7);
            bf16x8 af;
            af = __builtin_bit_cast(bf16x8,
                *(const u32x4*)(As + (wrow + lm) * BK + phys * 8));
            bf16x8 bfr[4];
#pragma unroll
            for (int ni = 0; ni < 4; ++ni)
                bfr[ni] = __builtin_bit_cast(bf16x8,
                    *(const u32x4*)(Bs + (ni * 16 + lm) * BK + phys * 8));
#pragma unroll
            for (int ni = 0; ni < 4; ++ni)
                acc[ni] = __builtin_amdgcn_mfma_f32_16x16x32_bf16(
                    af, bfr[ni], acc[ni], 0, 0, 0);
        }
        __syncthreads();
    }

    // per-row index sum
    if (tid < BM) {
        int grow = rowbase + tid;
        float si = 0.f;
        if (grow < NNODES) {
            int e0 = rs[grow], e1 = rs[grow + 1];
            for (int e = e0; e < e1; ++e) si += (float)srcs[e];
        }
        s1t[tid] = si;
    }
    __syncthreads();

    // epilogue -> LDS h2 tile
#pragma unroll
    for (int ni = 0; ni < 4; ++ni) {
        int gc = ni * 16 + lm;
        float r1v = r1[gc], r2v = r2[gc], bv = bias[gc];
#pragma unroll
        for (int r = 0; r < 4; ++r) {
            int lrow = wrow + quad * 4 + r;
            int grow = rowbase + lrow;
            float v = acc[ni][r] + s1t[lrow] * r1v + (float)grow * r2v + bv;
            v = (v >= 0.f) ? v : 0.01f * v;
            h2t[lrow * 65 + gc] = v;
        }
    }
    __syncthreads();

    // head: threads 0..63, one row each
    if (tid < BM) {
        int grow = rowbase + tid;
        if (grow < NNODES) {
            const float* hv = h2t + tid * 65;
            float idx = (float)grow;
            float p0 = 0.f, p1 = 0.f, p2 = 0.f;
            float r0 = 0.f, r1a = 0.f, r2a = 0.f, r3 = 0.f;
#pragma unroll 8
            for (int c = 0; c < 64; ++c) {
                float v = hv[c];
                p0 += v * Wp[c * 3 + 0];
                p1 += v * Wp[c * 3 + 1];
                p2 += v * Wp[c * 3 + 2];
                r0 += v * Wr[c * 4 + 0];
                r1a += v * Wr[c * 4 + 1];
                r2a += v * Wr[c * 4 + 2];
                r3 += v * Wr[c * 4 + 3];
            }
            p0 += idx * Wp[64 * 3 + 0] + bp[0];
            p1 += idx * Wp[64 * 3 + 1] + bp[1];
            p2 += idx * Wp[64 * 3 + 2] + bp[2];
            r0 += idx * Wr[64 * 4 + 0] + br[0];
            r1a += idx * Wr[64 * 4 + 1] + br[1];
            r2a += idx * Wr[64 * 4 + 2] + br[2];
            r3 += idx * Wr[64 * 4 + 3] + br[3];
            float nrm = fmaxf(sqrtf(r0 * r0 + r1a * r1a + r2a * r2a + r3 * r3), 1e-12f);
            float* op = out + (size_t)grow * 7;
            op[0] = p0; op[1] = p1; op[2] = p2;
            op[3] = r0 / nrm; op[4] = r1a / nrm; op[5] = r2a / nrm; op[6] = r3 / nrm;
        }
    }
}

extern "C" void kernel_launch(void* const* d_in, const int* in_sizes, int n_in,
                              void* d_out, int out_size, void* d_ws, size_t ws_size,
                              hipStream_t stream) {
    const float* x       = (const float*)d_in[0];
    const float* W1_rel  = (const float*)d_in[1];
    const float* b1      = (const float*)d_in[2];
    const float* W1_root = (const float*)d_in[3];
    const float* W2_rel  = (const float*)d_in[4];
    const float* b2      = (const float*)d_in[5];
    const float* W2_root = (const float*)d_in[6];
    const float* Wp      = (const float*)d_in[7];
    const float* bp      = (const float*)d_in[8];
    const float* Wr      = (const float*)d_in[9];
    const float* br      = (const float*)d_in[10];
    const int*   ei      = (const int*)d_in[11];
    float* out = (float*)d_out;

    char* ws = (char*)d_ws;
    size_t off = 0;
    auto alloc = [&](size_t bytes) {
        size_t o = off;
        off = (off + bytes + 255) & ~(size_t)255;
        return (void*)(ws + o);
    };
    int*   deg       = (int*)alloc(NNODES * 4);
    int*   cursor    = (int*)alloc(NNODES * 4);
    int*   row_start = (int*)alloc((NNODES + 1) * 4);
    int*   srcs      = (int*)alloc(NEDGES * 4);
    int*   partials  = (int*)alloc(NSCANB * 4);
    unsigned short* xb     = (unsigned short*)alloc((size_t)NNODES * 512 * 2);
    unsigned short* AggBuf = (unsigned short*)alloc((size_t)NNODES * 512 * 2);
    unsigned short* H1     = (unsigned short*)alloc((size_t)NNODES * 256 * 2);
    unsigned short* Seg    = (unsigned short*)alloc((size_t)NNODES * 256 * 2);
    unsigned short* Bt1    = (unsigned short*)alloc(256 * 1024 * 2);
    unsigned short* Bt2    = (unsigned short*)alloc(64 * 512 * 2);

    hipMemsetAsync(deg, 0, NNODES * 4, stream);

    k_prepcount<<<2048, 256, 0, stream>>>(
        x, W1_rel, W1_root, W2_rel, W2_root, ei, deg, Bt1, Bt2, xb);

    k_scanA<<<NSCANB, 256, 0, stream>>>(deg, row_start, partials);
    k_scanC2<<<NSCANB, 256, 0, stream>>>(row_start, partials, cursor);
    k_scatter<<<(NEDGES + 255) / 256, 256, 0, stream>>>(ei, cursor, srcs);

    k_agg1<<<NNODES / 4, 256, 0, stream>>>(xb, row_start, srcs, AggBuf);

    // GEMM1: [AggBuf | xb] @ Bt1^T -> H1 (bf16, stride 256). grid (col, row)
    k_gemm1<<<dim3(2, (NNODES + 63) / 64), 256, 0, stream>>>(
        AggBuf, xb, Bt1, row_start, srcs, W1_rel + 512 * 256, W1_root + 512 * 256, b1, H1);

    k_agg2<<<NNODES / 4, 256, 0, stream>>>(row_start, srcs, H1, Seg);

    // GEMM2 + head: [Seg | H1] @ Bt2^T -> out
    k_gemm2h<<<(NNODES + 63) / 64, 256, 0, stream>>>(
        Seg, H1, Bt2, row_start, srcs, W2_rel + 256 * 64, W2_root + 256 * 64, b2,
        Wp, bp, Wr, br, out);
}